// Round 22
// baseline (115.570 us; speedup 1.0000x reference)
//
#include <hip/hip_runtime.h>
#include <hip/hip_bf16.h>
#include <math.h>

#define T_    100
#define D_    50
#define H_    30
#define HALF  5120
#define EMB_  20
#define NEMB_ 10
#define OUT_  10

typedef _Float16 h2    __attribute__((ext_vector_type(2)));
typedef _Float16 f16x8 __attribute__((ext_vector_type(8)));
typedef float    f32x4 __attribute__((ext_vector_type(4)));

union FR  { f16x8 v; h2 p[4]; float4 f4; };

__device__ __forceinline__ h2 pk(float a, float b) {
    return __builtin_bit_cast(h2, __builtin_amdgcn_cvt_pkrtz(a, b));
}
__device__ __forceinline__ int pki(float a, float b) {
    return __builtin_bit_cast(int, __builtin_amdgcn_cvt_pkrtz(a, b));
}

#if __has_builtin(__builtin_amdgcn_exp2f)
#define EXP2(x) __builtin_amdgcn_exp2f(x)
#else
#define EXP2(x) exp2f(x)
#endif

struct XR { float2 a0, a1, a2, a3, b0, b1, b2, b3; };

// rho(j) = (j&3) + 4*(j>>3) + 16*((j>>2)&1): weight row (g,j) at ge = g*32+rho(j).
// Ext-tile (2g+u) holds gate g for j = 8q+4u+r at lane (s,q). A FULL step
// (all 6 tiles) leaves the lane self-sufficient (complete k-slice 8q..8q+7);
// a SPLIT step (3 tiles of parity wv) requires a partner exchange.
__device__ __forceinline__ int rho(int j) {
    return (j & 3) + 4 * (j >> 3) + 16 * ((j >> 2) & 1);
}

// ---------------------------------------------------------------------------
// GRU round 22: R20's hybrid split/full schedule (1 barrier per 2 steps)
// with the rule-#20 fix. R20's 24 MB "spill" was hold8[wv*4+r] —
// RUNTIME-indexed register array -> scratch. Here: holdM/holdO statically
// indexed, distributed via wave-uniform if(wv) branches; split-tile choice
// via uniform branches on LITERAL indices (never wih[wv]). Logic identical
// to R20 (which passed absmax 0.0039) — this is the clean barrier test.
// Block = 128 thr = 2 waves = 16 seqs, 640 blocks (1280 waves).
// ---------------------------------------------------------------------------
__global__ __launch_bounds__(128, 1) void gru_kernel(
    const float* __restrict__ input1, const float* __restrict__ input2,
    const float* __restrict__ W_ih,  const float* __restrict__ W_hh,
    const float* __restrict__ b_ih,  const float* __restrict__ b_hh,
    float* __restrict__ emb1_out,    // [5120][30]
    float* __restrict__ h2_out)      // [5120][30]
{
    const int tid  = threadIdx.x;
    const int lane = tid & 63;
    const int wv   = tid >> 6;          // wave = u-half (0 or 1)
    const int s    = lane & 15;
    const int q    = lane >> 4;
    const int n    = blockIdx.x * 16 + s;

    __shared__ __align__(16) _Float16 Wst [96 * 64];  // W_ih ext (12 KB)
    __shared__ __align__(16) _Float16 Whst[96 * 32];  // W_hh ext (6 KB)
    __shared__ __align__(8)  int2     Hx[2][2][64];   // [parity][wave][s*4+q]

    const float SC_RZ = -1.4426950408889634f;   // -log2(e)
    const float SC_N  =  2.8853900817779268f;   // +2*log2(e)

    for (int i = tid; i < 1536; i += 128) ((unsigned long long*)Wst)[i]  = 0ull;
    for (int i = tid; i < 768;  i += 128) ((unsigned long long*)Whst)[i] = 0ull;
    __syncthreads();

    for (int i = 0; i < 36; ++i) {
        int idx = tid + i * 128;
        if (idx < 4500) {
            int rw = idx / 50, k = idx - rw * 50;
            int g  = rw / 30,  j = rw - g * 30;
            int ge = g * 32 + rho(j);
            float sc = (g < 2) ? SC_RZ : SC_N;
            Wst[ge * 64 + k] = (_Float16)(W_ih[idx] * sc);
        }
    }
    if (tid < 90) {
        int g = tid / 30, j = tid - g * 30;
        int ge = g * 32 + rho(j);
        float sc = (g < 2) ? SC_RZ : SC_N;
        Wst[ge * 64 + 50] = (_Float16)(b_ih[tid] * sc);
    }
    for (int i = 0; i < 22; ++i) {
        int idx = tid + i * 128;
        if (idx < 2700) {
            int rw = idx / 30, k = idx - rw * 30;
            int g  = rw / 30,  j = rw - g * 30;
            int ge = g * 32 + rho(j);
            float sc = (g < 2) ? SC_RZ : SC_N;
            Whst[ge * 32 + k] = (_Float16)(W_hh[idx] * sc);
        }
    }
    if (tid < 90) {
        int g = tid / 30, j = tid - g * 30;
        int ge = g * 32 + rho(j);
        float sc = (g < 2) ? SC_RZ : SC_N;
        Whst[ge * 32 + 30] = (_Float16)(b_hh[tid] * sc);
    }
    __syncthreads();

    // ---- ALL 6 ext-tiles resident (literal indices only) ----
    FR wih[6][2], whh6[6];
    #pragma unroll
    for (int nt = 0; nt < 6; ++nt) {
        wih[nt][0].f4 = *(const float4*)&Wst [(nt * 16 + s) * 64 + q * 8];
        wih[nt][1].f4 = *(const float4*)&Wst [(nt * 16 + s) * 64 + 32 + q * 8];
        whh6[nt].f4   = *(const float4*)&Whst[(nt * 16 + s) * 32 + q * 8];
    }

    const float* xp = (n < HALF) ? input1 + (size_t)n * (T_ * D_)
                                 : input2 + (size_t)(n - HALF) * (T_ * D_);

    auto load_x = [&](int t, XR& X) {
        const float* r  = xp + t * D_;
        const float* pa = r + q * 8;
        const float* pb = (q < 2) ? (r + 32 + q * 8) : r;
        const float* p0 = (q == 2) ? (r + 48) : pb;
        X.a0 = *(const float2*)(pa + 0);
        X.a1 = *(const float2*)(pa + 2);
        X.a2 = *(const float2*)(pa + 4);
        X.a3 = *(const float2*)(pa + 6);
        X.b0 = *(const float2*)(p0);
        X.b1 = *(const float2*)(pb + 2);
        X.b2 = *(const float2*)(pb + 4);
        X.b3 = *(const float2*)(pb + 6);
    };
    auto build = [&](const XR& X, FR& x0, FR& x1) {
        x0.p[0] = pk(X.a0.x, X.a0.y); x0.p[1] = pk(X.a1.x, X.a1.y);
        x0.p[2] = pk(X.a2.x, X.a2.y); x0.p[3] = pk(X.a3.x, X.a3.y);
        if (q < 2) {
            x1.p[0] = pk(X.b0.x, X.b0.y); x1.p[1] = pk(X.b1.x, X.b1.y);
            x1.p[2] = pk(X.b2.x, X.b2.y); x1.p[3] = pk(X.b3.x, X.b3.y);
        } else if (q == 2) {
            x1.p[0] = pk(X.b0.x, X.b0.y); x1.p[1] = pk(1.f, 0.f);  // d48,49 | d50=bias
            x1.p[2] = pk(0.f, 0.f);       x1.p[3] = pk(0.f, 0.f);
        } else {
            x1.p[0] = pk(0.f, 0.f); x1.p[1] = pk(0.f, 0.f);
            x1.p[2] = pk(0.f, 0.f); x1.p[3] = pk(0.f, 0.f);
        }
    };

    // h state: holdM = own half (j = 8q+4wv+r, exact f32),
    //          holdO = partner half (f16-refreshed or full-step computed).
    float holdM[4] = {0.f, 0.f, 0.f, 0.f};
    float holdO[4] = {0.f, 0.f, 0.f, 0.f};
    int2 mine   = {0, 0};
    int2 theirs = {0, 0};
    const int ONE  = pki(1.f, 0.f);
    const int hidx = s * 4 + q;

    auto make_bh = [&]() -> FR {
        const int p0 = wv ? theirs.x : mine.x;
        const int p1 = wv ? theirs.y : mine.y;
        const int p2 = wv ? mine.x   : theirs.x;
        const int p3 = wv ? mine.y   : theirs.y;
        FR bh;
        bh.p[0] = __builtin_bit_cast(h2, p0);
        bh.p[1] = __builtin_bit_cast(h2, p1);
        bh.p[2] = __builtin_bit_cast(h2, p2);
        bh.p[3] = __builtin_bit_cast(h2, q == 3 ? ONE : p3);
        return bh;
    };

    auto xphase_full = [&](XR& X, int tload, f32x4 (&xF)[6]) {
        FR x0, x1;
        build(X, x0, x1);
        load_x(tload, X);
        #pragma unroll
        for (int i = 0; i < 6; ++i) {
            f32x4 zz = {0.f, 0.f, 0.f, 0.f};
            f32x4 a = __builtin_amdgcn_mfma_f32_16x16x32_f16(wih[i][0].v, x0.v, zz, 0, 0, 0);
            xF[i] = __builtin_amdgcn_mfma_f32_16x16x32_f16(wih[i][1].v, x1.v, a, 0, 0, 0);
        }
    };
    auto xphase_split = [&](XR& X, int tload, f32x4 (&xS)[3]) {
        FR x0, x1;
        build(X, x0, x1);
        load_x(tload, X);
        f32x4 zz = {0.f, 0.f, 0.f, 0.f};
        f32x4 a;
        if (wv == 0) {          // literal tile indices in each uniform branch
            a = __builtin_amdgcn_mfma_f32_16x16x32_f16(wih[0][0].v, x0.v, zz, 0, 0, 0);
            xS[0] = __builtin_amdgcn_mfma_f32_16x16x32_f16(wih[0][1].v, x1.v, a, 0, 0, 0);
            a = __builtin_amdgcn_mfma_f32_16x16x32_f16(wih[2][0].v, x0.v, zz, 0, 0, 0);
            xS[1] = __builtin_amdgcn_mfma_f32_16x16x32_f16(wih[2][1].v, x1.v, a, 0, 0, 0);
            a = __builtin_amdgcn_mfma_f32_16x16x32_f16(wih[4][0].v, x0.v, zz, 0, 0, 0);
            xS[2] = __builtin_amdgcn_mfma_f32_16x16x32_f16(wih[4][1].v, x1.v, a, 0, 0, 0);
        } else {
            a = __builtin_amdgcn_mfma_f32_16x16x32_f16(wih[1][0].v, x0.v, zz, 0, 0, 0);
            xS[0] = __builtin_amdgcn_mfma_f32_16x16x32_f16(wih[1][1].v, x1.v, a, 0, 0, 0);
            a = __builtin_amdgcn_mfma_f32_16x16x32_f16(wih[3][0].v, x0.v, zz, 0, 0, 0);
            xS[1] = __builtin_amdgcn_mfma_f32_16x16x32_f16(wih[3][1].v, x1.v, a, 0, 0, 0);
            a = __builtin_amdgcn_mfma_f32_16x16x32_f16(wih[5][0].v, x0.v, zz, 0, 0, 0);
            xS[2] = __builtin_amdgcn_mfma_f32_16x16x32_f16(wih[5][1].v, x1.v, a, 0, 0, 0);
        }
    };

    // ---- split step: own 3 tiles, 4-elem gates, exchange (the barrier) ----
    auto split_step = [&](const f32x4 (&xS)[3], int par) {
        FR bh = make_bh();
        f32x4 zz = {0.f, 0.f, 0.f, 0.f};
        f32x4 ar, az, anh;
        if (wv == 0) {
            ar  = __builtin_amdgcn_mfma_f32_16x16x32_f16(whh6[0].v, bh.v, xS[0], 0, 0, 0);
            az  = __builtin_amdgcn_mfma_f32_16x16x32_f16(whh6[2].v, bh.v, xS[1], 0, 0, 0);
            anh = __builtin_amdgcn_mfma_f32_16x16x32_f16(whh6[4].v, bh.v, zz,    0, 0, 0);
        } else {
            ar  = __builtin_amdgcn_mfma_f32_16x16x32_f16(whh6[1].v, bh.v, xS[0], 0, 0, 0);
            az  = __builtin_amdgcn_mfma_f32_16x16x32_f16(whh6[3].v, bh.v, xS[1], 0, 0, 0);
            anh = __builtin_amdgcn_mfma_f32_16x16x32_f16(whh6[5].v, bh.v, zz,    0, 0, 0);
        }
        #pragma unroll
        for (int r = 0; r < 4; ++r) {
            const float er = EXP2(ar[r]);
            const float rg = __builtin_amdgcn_rcpf(1.f + er);
            const float ez = EXP2(az[r]);
            const float aa = fmaf(rg, anh[r], xS[2][r]);
            const float et = EXP2(aa);
            const float oz = 1.f + ez, ot = 1.f + et;
            const float ip = __builtin_amdgcn_rcpf(oz * ot);
            const float zg = ot * ip;
            const float th = fmaf(-2.f * oz, ip, 1.f);
            holdM[r] = fmaf(zg, holdM[r] - th, th);
        }
        mine.x = pki(holdM[0], holdM[1]);
        mine.y = pki(holdM[2], holdM[3]);
        Hx[par][wv][hidx] = mine;
        asm volatile("s_waitcnt lgkmcnt(0)" ::: "memory");
        __builtin_amdgcn_s_barrier();                   // raw: no vmcnt drain
        __builtin_amdgcn_sched_barrier(0);
        theirs = Hx[par][wv ^ 1][hidx];
        h2 t0 = __builtin_bit_cast(h2, theirs.x);
        h2 t1 = __builtin_bit_cast(h2, theirs.y);
        holdO[0] = (float)t0[0]; holdO[1] = (float)t0[1];
        holdO[2] = (float)t1[0]; holdO[3] = (float)t1[1];
    };

    // ---- full step: all 6 tiles, 8-elem gates, NO barrier ----
    auto full_step = [&](const f32x4 (&xF)[6]) {
        FR bh = make_bh();
        f32x4 arz[4], ah[2];
        #pragma unroll
        for (int nt = 0; nt < 4; ++nt)
            arz[nt] = __builtin_amdgcn_mfma_f32_16x16x32_f16(whh6[nt].v, bh.v, xF[nt], 0, 0, 0);
        #pragma unroll
        for (int u = 0; u < 2; ++u) {
            f32x4 zz = {0.f, 0.f, 0.f, 0.f};
            ah[u] = __builtin_amdgcn_mfma_f32_16x16x32_f16(whh6[4 + u].v, bh.v, zz, 0, 0, 0);
        }
        float nn0[4], nn1[4];                  // halves u=0, u=1 (static idx)
        #pragma unroll
        for (int r = 0; r < 4; ++r) {
            {   // u = 0
                const float er = EXP2(arz[0][r]);
                const float rg = __builtin_amdgcn_rcpf(1.f + er);
                const float ez = EXP2(arz[2][r]);
                const float aa = fmaf(rg, ah[0][r], xF[4][r]);
                const float et = EXP2(aa);
                const float oz = 1.f + ez, ot = 1.f + et;
                const float ip = __builtin_amdgcn_rcpf(oz * ot);
                const float zg = ot * ip;
                const float th = fmaf(-2.f * oz, ip, 1.f);
                const float ho = (wv == 0) ? holdM[r] : holdO[r];
                nn0[r] = fmaf(zg, ho - th, th);
            }
            {   // u = 1
                const float er = EXP2(arz[1][r]);
                const float rg = __builtin_amdgcn_rcpf(1.f + er);
                const float ez = EXP2(arz[3][r]);
                const float aa = fmaf(rg, ah[1][r], xF[5][r]);
                const float et = EXP2(aa);
                const float oz = 1.f + ez, ot = 1.f + et;
                const float ip = __builtin_amdgcn_rcpf(oz * ot);
                const float zg = ot * ip;
                const float th = fmaf(-2.f * oz, ip, 1.f);
                const float ho = (wv == 1) ? holdM[r] : holdO[r];
                nn1[r] = fmaf(zg, ho - th, th);
            }
        }
        if (wv == 0) {
            #pragma unroll
            for (int r = 0; r < 4; ++r) { holdM[r] = nn0[r]; holdO[r] = nn1[r]; }
        } else {
            #pragma unroll
            for (int r = 0; r < 4; ++r) { holdM[r] = nn1[r]; holdO[r] = nn0[r]; }
        }
        mine.x   = pki(holdM[0], holdM[1]);
        mine.y   = pki(holdM[2], holdM[3]);
        theirs.x = pki(holdO[0], holdO[1]);
        theirs.y = pki(holdO[2], holdO[3]);
    };

    // ---- prologue: X0..X3 = x(0..3); xaccS for t=0; X0 -> x(4) ----
    XR X0, X1, X2, X3;
    load_x(0, X0); load_x(1, X1); load_x(2, X2); load_x(3, X3);
    f32x4 xaccS[3], xaccF[6];
    xphase_split(X0, 4, xaccS);

    // ---- 100 steps = 25 x [split, full, split, full]; 50 barriers total ----
    #pragma unroll 1
    for (int k = 0; k < 25; ++k) {
        const int t = 4 * k;
        xphase_full(X1, (t + 5 < 100 ? t + 5 : 99), xaccF);
        split_step(xaccS, 0);                          // step t
        xphase_split(X2, (t + 6 < 100 ? t + 6 : 99), xaccS);
        full_step(xaccF);                              // step t+1
        xphase_full(X3, (t + 7 < 100 ? t + 7 : 99), xaccF);
        split_step(xaccS, 1);                          // step t+2
        xphase_split(X0, (t + 8 < 100 ? t + 8 : 99), xaccS);
        full_step(xaccF);                              // step t+3
    }

    // ---- final hidden out: own half j = 8q + 4*wv + r ----
    float* outp = (n < HALF) ? emb1_out + (size_t)n * H_
                             : h2_out + (size_t)(n - HALF) * H_;
    #pragma unroll
    for (int r = 0; r < 4; ++r) {
        const int j = 8 * q + 4 * wv + r;
        if (j < H_) outp[j] = holdM[r];
    }
}

// ---------------------------------------------------------------------------
__global__ __launch_bounds__(64) void mlp_kernel(
    const float* __restrict__ h2i,
    const float* __restrict__ W1, const float* __restrict__ b1,
    const float* __restrict__ W2, const float* __restrict__ b2,
    const float* __restrict__ W3, const float* __restrict__ b3,
    float* __restrict__ logit)
{
    const int b    = blockIdx.x;
    const int lane = threadIdx.x;
    __shared__ float e2[300];
    const float* row = h2i + (size_t)b * 300;
    #pragma unroll
    for (int i = lane; i < 75; i += 64)
        *(float4*)&e2[i * 4] = *(const float4*)(row + i * 4);
    __syncthreads();

    const float kInvSqrt2 = 0.70710678118654752f;
    float y1 = 0.f;
    if (lane < EMB_) {
        float acc = b1[lane];
        const float* wp = W1 + lane * 300;
        #pragma unroll
        for (int qq = 0; qq < 75; ++qq) {
            float4 wv = *(const float4*)(wp + qq * 4);
            acc += wv.x * e2[qq*4 + 0] + wv.y * e2[qq*4 + 1]
                 + wv.z * e2[qq*4 + 2] + wv.w * e2[qq*4 + 3];
        }
        y1 = 0.5f * acc * (1.f + erff(acc * kInvSqrt2));
    }
    float acc2 = (lane < NEMB_) ? b2[lane] : 0.f;
    #pragma unroll
    for (int e = 0; e < EMB_; ++e) {
        const float v = __shfl(y1, e);
        if (lane < NEMB_) acc2 += v * W2[lane * EMB_ + e];
    }
    const float y2 = 0.5f * acc2 * (1.f + erff(acc2 * kInvSqrt2));
    float acc3 = (lane < OUT_) ? b3[lane] : 0.f;
    #pragma unroll
    for (int e = 0; e < NEMB_; ++e) {
        const float v = __shfl(y2, e);
        if (lane < OUT_) acc3 += v * W3[lane * NEMB_ + e];
    }
    if (lane < OUT_) logit[(size_t)b * OUT_ + lane] = acc3;
}

// ---------------------------------------------------------------------------
extern "C" void kernel_launch(void* const* d_in, const int* in_sizes, int n_in,
                              void* d_out, int out_size, void* d_ws, size_t ws_size,
                              hipStream_t stream) {
    const float* input1 = (const float*)d_in[0];
    const float* input2 = (const float*)d_in[1];
    const float* W_ih   = (const float*)d_in[2];
    const float* W_hh   = (const float*)d_in[3];
    const float* b_ih   = (const float*)d_in[4];
    const float* b_hh   = (const float*)d_in[5];
    const float* W1     = (const float*)d_in[6];
    const float* b1     = (const float*)d_in[7];
    const float* W2     = (const float*)d_in[8];
    const float* b2     = (const float*)d_in[9];
    const float* W3     = (const float*)d_in[10];
    const float* b3     = (const float*)d_in[11];

    float* out = (float*)d_out;
    float* h2s = (float*)d_ws;

    hipLaunchKernelGGL(gru_kernel, dim3(640), dim3(128), 0, stream,
                       input1, input2, W_ih, W_hh, b_ih, b_hh,
                       out + 5120, h2s);
    hipLaunchKernelGGL(mlp_kernel, dim3(512), dim3(64), 0, stream,
                       h2s, W1, b1, W2, b2, W3, b3, out);
}

// Round 23
// 96.644 us; speedup vs baseline: 1.1958x; 1.1958x over previous
//
#include <hip/hip_runtime.h>
#include <hip/hip_bf16.h>
#include <math.h>

#define T_    100
#define D_    50
#define H_    30
#define HALF  5120
#define EMB_  20
#define NEMB_ 10
#define OUT_  10

typedef _Float16 h2    __attribute__((ext_vector_type(2)));
typedef _Float16 f16x8 __attribute__((ext_vector_type(8)));
typedef float    f32x4 __attribute__((ext_vector_type(4)));

union FR  { f16x8 v; h2 p[4]; float4 f4; };

__device__ __forceinline__ h2 pk(float a, float b) {
    return __builtin_bit_cast(h2, __builtin_amdgcn_cvt_pkrtz(a, b));
}
__device__ __forceinline__ int pki(float a, float b) {
    return __builtin_bit_cast(int, __builtin_amdgcn_cvt_pkrtz(a, b));
}

#if __has_builtin(__builtin_amdgcn_exp2f)
#define EXP2(x) __builtin_amdgcn_exp2f(x)
#else
#define EXP2(x) exp2f(x)
#endif

struct XR { float2 a0, a1, a2, a3, b0, b1, b2, b3; };

// rho(j) = (j&3) + 4*(j>>3) + 16*((j>>2)&1): weight row (g,j) at ge = g*32+rho(j).
// MFMA C-layout => lane (s,q) of tile nt holds ge = nt*16 + 4q + r, i.e.
// j = 8q + 4*(tile parity) + r. Tile-parity u IS the wave split axis:
// wave u owns j = 8q+4u+r and needs only the partner's 2 packed dwords
// (the other half of k-slice 8q..8q+7) to rebuild its B-fragment.
__device__ __forceinline__ int rho(int j) {
    return (j & 3) + 4 * (j >> 3) + 16 * ((j >> 2) & 1);
}

// ---------------------------------------------------------------------------
// GRU (final = round-19 best, 96.8 us clean, reproduced twice): 2-wave
// gate-row split. Block = 128 thr = 2 waves = 16 seqs, 640 blocks ->
// 1280 waves, per-wave work halved (9 MFMAs, 4-elem gates, ~20 trans)
// with total work unchanged.
// Falsified alternatives (kept for the record): deeper prefetch/counted
// vmcnt (R8-R10), shuffle h-redistribution (R7), 2-group software ILP
// (R12), TLP-by-duplication (R15), TA-coalescing via LDS/global_load_lds
// (R17/R18), barrier-halving hybrid (R20 spill / R22 clean: net loss).
// Wins kept: MFMA recurrence (R4), rho-permutation shuffle-free h (R13),
// merged z/tanh rcp + exp2-folded weights (R16), this wave split (R19).
// Per-step exchange: ds_write_b64(own pair) -> lgkmcnt(0) -> raw s_barrier
// (NOT __syncthreads: would vmcnt-drain the x prefetch) -> ds_read_b64
// (partner pair), double-buffered by step parity (WAR-safe over 2 barriers).
// Biases folded into MFMA (Hext[30]=1 -> b_hh, x[50]=1 -> b_ih).
// ---------------------------------------------------------------------------
__global__ __launch_bounds__(128, 1) void gru_kernel(
    const float* __restrict__ input1, const float* __restrict__ input2,
    const float* __restrict__ W_ih,  const float* __restrict__ W_hh,
    const float* __restrict__ b_ih,  const float* __restrict__ b_hh,
    float* __restrict__ emb1_out,    // [5120][30]
    float* __restrict__ h2_out)      // [5120][30]
{
    const int tid  = threadIdx.x;
    const int lane = tid & 63;
    const int wv   = tid >> 6;          // wave = u-half (0 or 1)
    const int s    = lane & 15;
    const int q    = lane >> 4;
    const int n    = blockIdx.x * 16 + s;

    __shared__ __align__(16) _Float16 Wst [96 * 64];  // W_ih ext (12 KB)
    __shared__ __align__(16) _Float16 Whst[96 * 32];  // W_hh ext (6 KB)
    __shared__ __align__(8)  int2     Hx[2][2][64];   // [parity][wave][s*4+q]

    const float SC_RZ = -1.4426950408889634f;   // -log2(e)
    const float SC_N  =  2.8853900817779268f;   // +2*log2(e)

    for (int i = tid; i < 1536; i += 128) ((unsigned long long*)Wst)[i]  = 0ull;
    for (int i = tid; i < 768;  i += 128) ((unsigned long long*)Whst)[i] = 0ull;
    __syncthreads();

    for (int i = 0; i < 36; ++i) {
        int idx = tid + i * 128;
        if (idx < 4500) {
            int rw = idx / 50, k = idx - rw * 50;
            int g  = rw / 30,  j = rw - g * 30;
            int ge = g * 32 + rho(j);
            float sc = (g < 2) ? SC_RZ : SC_N;
            Wst[ge * 64 + k] = (_Float16)(W_ih[idx] * sc);
        }
    }
    if (tid < 90) {
        int g = tid / 30, j = tid - g * 30;
        int ge = g * 32 + rho(j);
        float sc = (g < 2) ? SC_RZ : SC_N;
        Wst[ge * 64 + 50] = (_Float16)(b_ih[tid] * sc);
    }
    for (int i = 0; i < 22; ++i) {
        int idx = tid + i * 128;
        if (idx < 2700) {
            int rw = idx / 30, k = idx - rw * 30;
            int g  = rw / 30,  j = rw - g * 30;
            int ge = g * 32 + rho(j);
            float sc = (g < 2) ? SC_RZ : SC_N;
            Whst[ge * 32 + k] = (_Float16)(W_hh[idx] * sc);
        }
    }
    if (tid < 90) {
        int g = tid / 30, j = tid - g * 30;
        int ge = g * 32 + rho(j);
        float sc = (g < 2) ? SC_RZ : SC_N;
        Whst[ge * 32 + 30] = (_Float16)(b_hh[tid] * sc);
    }
    __syncthreads();

    // ---- this wave's 3 tiles: r-tile wv, z-tile 2+wv, n-tile 4+wv ----
    const int tR = wv, tZ = 2 + wv, tN = 4 + wv;
    FR wihR0, wihR1, wihZ0, wihZ1, wihN0, wihN1, whhR, whhZ, whhN;
    wihR0.f4 = *(const float4*)&Wst [(tR * 16 + s) * 64 + q * 8];
    wihR1.f4 = *(const float4*)&Wst [(tR * 16 + s) * 64 + 32 + q * 8];
    wihZ0.f4 = *(const float4*)&Wst [(tZ * 16 + s) * 64 + q * 8];
    wihZ1.f4 = *(const float4*)&Wst [(tZ * 16 + s) * 64 + 32 + q * 8];
    wihN0.f4 = *(const float4*)&Wst [(tN * 16 + s) * 64 + q * 8];
    wihN1.f4 = *(const float4*)&Wst [(tN * 16 + s) * 64 + 32 + q * 8];
    whhR.f4  = *(const float4*)&Whst[(tR * 16 + s) * 32 + q * 8];
    whhZ.f4  = *(const float4*)&Whst[(tZ * 16 + s) * 32 + q * 8];
    whhN.f4  = *(const float4*)&Whst[(tN * 16 + s) * 32 + q * 8];

    const float* xp = (n < HALF) ? input1 + (size_t)n * (T_ * D_)
                                 : input2 + (size_t)(n - HALF) * (T_ * D_);

    auto load_x = [&](int t, XR& X) {
        const float* r  = xp + t * D_;
        const float* pa = r + q * 8;
        const float* pb = (q < 2) ? (r + 32 + q * 8) : r;
        const float* p0 = (q == 2) ? (r + 48) : pb;
        X.a0 = *(const float2*)(pa + 0);
        X.a1 = *(const float2*)(pa + 2);
        X.a2 = *(const float2*)(pa + 4);
        X.a3 = *(const float2*)(pa + 6);
        X.b0 = *(const float2*)(p0);
        X.b1 = *(const float2*)(pb + 2);
        X.b2 = *(const float2*)(pb + 4);
        X.b3 = *(const float2*)(pb + 6);
    };
    auto build = [&](const XR& X, FR& x0, FR& x1) {
        x0.p[0] = pk(X.a0.x, X.a0.y); x0.p[1] = pk(X.a1.x, X.a1.y);
        x0.p[2] = pk(X.a2.x, X.a2.y); x0.p[3] = pk(X.a3.x, X.a3.y);
        if (q < 2) {
            x1.p[0] = pk(X.b0.x, X.b0.y); x1.p[1] = pk(X.b1.x, X.b1.y);
            x1.p[2] = pk(X.b2.x, X.b2.y); x1.p[3] = pk(X.b3.x, X.b3.y);
        } else if (q == 2) {
            x1.p[0] = pk(X.b0.x, X.b0.y); x1.p[1] = pk(1.f, 0.f);  // d48,49 | d50=bias
            x1.p[2] = pk(0.f, 0.f);       x1.p[3] = pk(0.f, 0.f);
        } else {
            x1.p[0] = pk(0.f, 0.f); x1.p[1] = pk(0.f, 0.f);
            x1.p[2] = pk(0.f, 0.f); x1.p[3] = pk(0.f, 0.f);
        }
    };

    float hold[4] = {0.f, 0.f, 0.f, 0.f};
    int2 mine   = {0, 0};                // own packed h pair (j = 8q+4wv+0..3)
    int2 theirs = {0, 0};                // partner's pair
    const int ONE  = pki(1.f, 0.f);      // Hext k=30 bias (q==3)
    const int hidx = s * 4 + q;

    auto xphase = [&](XR& X, int tload, f32x4 (&xacc)[3]) {
        FR x0, x1;
        build(X, x0, x1);
        load_x(tload, X);
        f32x4 zz = {0.f, 0.f, 0.f, 0.f};
        f32x4 a;
        a = __builtin_amdgcn_mfma_f32_16x16x32_f16(wihR0.v, x0.v, zz, 0, 0, 0);
        xacc[0] = __builtin_amdgcn_mfma_f32_16x16x32_f16(wihR1.v, x1.v, a, 0, 0, 0);
        a = __builtin_amdgcn_mfma_f32_16x16x32_f16(wihZ0.v, x0.v, zz, 0, 0, 0);
        xacc[1] = __builtin_amdgcn_mfma_f32_16x16x32_f16(wihZ1.v, x1.v, a, 0, 0, 0);
        a = __builtin_amdgcn_mfma_f32_16x16x32_f16(wihN0.v, x0.v, zz, 0, 0, 0);
        xacc[2] = __builtin_amdgcn_mfma_f32_16x16x32_f16(wihN1.v, x1.v, a, 0, 0, 0);
    };
    auto step_h = [&](const f32x4 (&xacc)[3], f32x4& ar, f32x4& az, f32x4& anh) {
        // B-frag k-slices 8q..8q+7: wave0 owns low half, wave1 high half
        const int p0 = wv ? theirs.x : mine.x;
        const int p1 = wv ? theirs.y : mine.y;
        const int p2 = wv ? mine.x   : theirs.x;
        const int p3 = wv ? mine.y   : theirs.y;
        FR bh;
        bh.p[0] = __builtin_bit_cast(h2, p0);
        bh.p[1] = __builtin_bit_cast(h2, p1);
        bh.p[2] = __builtin_bit_cast(h2, p2);
        bh.p[3] = __builtin_bit_cast(h2, q == 3 ? ONE : p3);
        f32x4 zz = {0.f, 0.f, 0.f, 0.f};
        ar  = __builtin_amdgcn_mfma_f32_16x16x32_f16(whhR.v, bh.v, xacc[0], 0, 0, 0);
        az  = __builtin_amdgcn_mfma_f32_16x16x32_f16(whhZ.v, bh.v, xacc[1], 0, 0, 0);
        anh = __builtin_amdgcn_mfma_f32_16x16x32_f16(whhN.v, bh.v, zz,      0, 0, 0);
    };
    auto step_fin = [&](const f32x4& ar, const f32x4& az, const f32x4& anh,
                        const f32x4& anx) {
        #pragma unroll
        for (int r = 0; r < 4; ++r) {
            const float er = EXP2(ar[r]);
            const float rg = __builtin_amdgcn_rcpf(1.f + er);
            const float ez = EXP2(az[r]);
            const float aa = fmaf(rg, anh[r], anx[r]);
            const float et = EXP2(aa);
            const float oz = 1.f + ez, ot = 1.f + et;
            const float ip = __builtin_amdgcn_rcpf(oz * ot);
            const float zg = ot * ip;
            const float th = fmaf(-2.f * oz, ip, 1.f);
            hold[r] = fmaf(zg, hold[r] - th, th);
        }
        mine.x = pki(hold[0], hold[1]);
        mine.y = pki(hold[2], hold[3]);
    };
    auto exchange = [&](int par) {
        Hx[par][wv][hidx] = mine;                       // own h_t pair
        asm volatile("s_waitcnt lgkmcnt(0)" ::: "memory");
        __builtin_amdgcn_s_barrier();                   // raw: no vmcnt drain
        __builtin_amdgcn_sched_barrier(0);
        theirs = Hx[par][wv ^ 1][hidx];                 // partner h_t pair
    };

    // ---- prologue: X0..X3 = x(0..3); xaccA for t=0; X0 -> x(4) ----
    XR X0, X1, X2, X3;
    load_x(0, X0); load_x(1, X1); load_x(2, X2); load_x(3, X3);
    f32x4 xaccA[3], xaccB[3];
    {
        FR x0, x1;
        build(X0, x0, x1);
        load_x(4, X0);
        f32x4 zz = {0.f, 0.f, 0.f, 0.f};
        f32x4 a;
        a = __builtin_amdgcn_mfma_f32_16x16x32_f16(wihR0.v, x0.v, zz, 0, 0, 0);
        xaccA[0] = __builtin_amdgcn_mfma_f32_16x16x32_f16(wihR1.v, x1.v, a, 0, 0, 0);
        a = __builtin_amdgcn_mfma_f32_16x16x32_f16(wihZ0.v, x0.v, zz, 0, 0, 0);
        xaccA[1] = __builtin_amdgcn_mfma_f32_16x16x32_f16(wihZ1.v, x1.v, a, 0, 0, 0);
        a = __builtin_amdgcn_mfma_f32_16x16x32_f16(wihN0.v, x0.v, zz, 0, 0, 0);
        xaccA[2] = __builtin_amdgcn_mfma_f32_16x16x32_f16(wihN1.v, x1.v, a, 0, 0, 0);
    }

    // ---- 100 steps: 25 x 4-step body; parities 0,1,0,1 (t=4k even) ----
    #pragma unroll 1
    for (int k = 0; k < 25; ++k) {
        const int t = 4 * k;
        f32x4 ar, az, anh;
        step_h(xaccA, ar, az, anh);
        xphase(X1, (t + 5 < 100 ? t + 5 : 99), xaccB);
        step_fin(ar, az, anh, xaccA[2]);
        exchange(0);
        step_h(xaccB, ar, az, anh);
        xphase(X2, (t + 6 < 100 ? t + 6 : 99), xaccA);
        step_fin(ar, az, anh, xaccB[2]);
        exchange(1);
        step_h(xaccA, ar, az, anh);
        xphase(X3, (t + 7 < 100 ? t + 7 : 99), xaccB);
        step_fin(ar, az, anh, xaccA[2]);
        exchange(0);
        step_h(xaccB, ar, az, anh);
        xphase(X0, (t + 8 < 100 ? t + 8 : 99), xaccA);
        step_fin(ar, az, anh, xaccB[2]);
        exchange(1);
    }

    // ---- final hidden out: this wave's j = 8q + 4*wv + r ----
    float* outp = (n < HALF) ? emb1_out + (size_t)n * H_
                             : h2_out + (size_t)(n - HALF) * H_;
    #pragma unroll
    for (int r = 0; r < 4; ++r) {
        const int j = 8 * q + 4 * wv + r;
        if (j < H_) outp[j] = hold[r];
    }
}

// ---------------------------------------------------------------------------
__global__ __launch_bounds__(64) void mlp_kernel(
    const float* __restrict__ h2i,
    const float* __restrict__ W1, const float* __restrict__ b1,
    const float* __restrict__ W2, const float* __restrict__ b2,
    const float* __restrict__ W3, const float* __restrict__ b3,
    float* __restrict__ logit)
{
    const int b    = blockIdx.x;
    const int lane = threadIdx.x;
    __shared__ float e2[300];
    const float* row = h2i + (size_t)b * 300;
    #pragma unroll
    for (int i = lane; i < 75; i += 64)
        *(float4*)&e2[i * 4] = *(const float4*)(row + i * 4);
    __syncthreads();

    const float kInvSqrt2 = 0.70710678118654752f;
    float y1 = 0.f;
    if (lane < EMB_) {
        float acc = b1[lane];
        const float* wp = W1 + lane * 300;
        #pragma unroll
        for (int qq = 0; qq < 75; ++qq) {
            float4 wv = *(const float4*)(wp + qq * 4);
            acc += wv.x * e2[qq*4 + 0] + wv.y * e2[qq*4 + 1]
                 + wv.z * e2[qq*4 + 2] + wv.w * e2[qq*4 + 3];
        }
        y1 = 0.5f * acc * (1.f + erff(acc * kInvSqrt2));
    }
    float acc2 = (lane < NEMB_) ? b2[lane] : 0.f;
    #pragma unroll
    for (int e = 0; e < EMB_; ++e) {
        const float v = __shfl(y1, e);
        if (lane < NEMB_) acc2 += v * W2[lane * EMB_ + e];
    }
    const float y2 = 0.5f * acc2 * (1.f + erff(acc2 * kInvSqrt2));
    float acc3 = (lane < OUT_) ? b3[lane] : 0.f;
    #pragma unroll
    for (int e = 0; e < NEMB_; ++e) {
        const float v = __shfl(y2, e);
        if (lane < OUT_) acc3 += v * W3[lane * NEMB_ + e];
    }
    if (lane < OUT_) logit[(size_t)b * OUT_ + lane] = acc3;
}

// ---------------------------------------------------------------------------
extern "C" void kernel_launch(void* const* d_in, const int* in_sizes, int n_in,
                              void* d_out, int out_size, void* d_ws, size_t ws_size,
                              hipStream_t stream) {
    const float* input1 = (const float*)d_in[0];
    const float* input2 = (const float*)d_in[1];
    const float* W_ih   = (const float*)d_in[2];
    const float* W_hh   = (const float*)d_in[3];
    const float* b_ih   = (const float*)d_in[4];
    const float* b_hh   = (const float*)d_in[5];
    const float* W1     = (const float*)d_in[6];
    const float* b1     = (const float*)d_in[7];
    const float* W2     = (const float*)d_in[8];
    const float* b2     = (const float*)d_in[9];
    const float* W3     = (const float*)d_in[10];
    const float* b3     = (const float*)d_in[11];

    float* out = (float*)d_out;
    float* h2s = (float*)d_ws;

    hipLaunchKernelGGL(gru_kernel, dim3(640), dim3(128), 0, stream,
                       input1, input2, W_ih, W_hh, b_ih, b_hh,
                       out + 5120, h2s);
    hipLaunchKernelGGL(mlp_kernel, dim3(512), dim3(64), 0, stream,
                       h2s, W1, b1, W2, b2, W3, b3, out);
}